// Round 1
// baseline (4833.851 us; speedup 1.0000x reference)
//
#include <hip/hip_runtime.h>

#define D128 128
#define NT 101
#define NDHEADS 8
#define TDEC 256
#define KS_STRIDE 129
#define KP2_STRIDE 103

// LDS layout (floats)
#define KS_OFF   0
#define VS_OFF   (KS_OFF + NT*KS_STRIDE)
#define KP2_OFF  (VS_OFF + NT*KS_STRIDE)
#define SC_OFF   (KP2_OFF + 128*KP2_STRIDE)
#define QV_OFF   (SC_OFF + NDHEADS*NT)
#define O0_OFF   (QV_OFF + 128)
#define LG_OFF   (O0_OFF + 256)
#define LGP_OFF  (LG_OFF + 104)
#define MK_OFF   (LGP_OFF + 104)
#define MK1_OFF  (MK_OFF + 104)
#define BC_OFF   (MK1_OFF + 104)
#define LDS_FLOATS (BC_OFF + 32)

#define INV_D_CONST 0.08838834764831845f

__device__ __forceinline__ int read_scalar_int(const void* p){
    unsigned u = *(const unsigned*)p;
    if (u < 1000000u) return (int)u;          // stored as int32 (small value)
    return (int)__uint_as_float(u);           // stored as float32
}
__device__ __forceinline__ float read_scalar_float(const void* p){
    unsigned u = *(const unsigned*)p;
    if (u < 1000000u) return (float)(int)u;
    return __uint_as_float(u);
}

// ---------------- weight folding ----------------
// Wkp2[i][j] = sum_e prob_k[i][e]*attn_fc[j][e]        (so kp2 = enc @ Wkp2)
// Wqp [i][j] = sum_e fc_w[i][e]*attn_w[e][j]  (i<128)  (so QA = enc @ Wqp + pq)
// Wpq [i][j] = sum_e fc1_w[i][e]*attn_w[e][j]          (pq = pool @ Wpq)
// wlast[j]   = sum_e fc_w[128][e]*attn_w[e][j]         (q += dyn*wlast)
__global__ void prep_w(const float* __restrict__ fc_w, const float* __restrict__ fc1_w,
                       const float* __restrict__ attn_w, const float* __restrict__ prob_k,
                       const float* __restrict__ attn_fc,
                       float* __restrict__ Wkp2, float* __restrict__ Wqp,
                       float* __restrict__ Wpq, float* __restrict__ wlast){
    int r = blockIdx.x, j = threadIdx.x;
    if (r < 128){
        float acc = 0.f; const float* pr = prob_k + r*D128;
        for (int e = 0; e < D128; ++e) acc += pr[e]*attn_fc[j*D128+e];
        Wkp2[r*D128+j] = acc;
    } else if (r < 256){
        int rr = r-128; float acc = 0.f; const float* fr = fc_w + rr*D128;
        for (int e = 0; e < D128; ++e) acc += fr[e]*attn_w[e*D128+j];
        Wqp[rr*D128+j] = acc;
    } else if (r < 384){
        int rr = r-256; float acc = 0.f; const float* fr = fc1_w + rr*D128;
        for (int e = 0; e < D128; ++e) acc += fr[e]*attn_w[e*D128+j];
        Wpq[rr*D128+j] = acc;
    } else {
        float acc = 0.f; const float* fr = fc_w + 128*D128;
        for (int e = 0; e < D128; ++e) acc += fr[e]*attn_w[e*D128+j];
        wlast[j] = acc;
    }
}

__global__ void prep_pq(const float* __restrict__ pool, const float* __restrict__ Wpq,
                        float* __restrict__ pq){
    int b = blockIdx.x, j = threadIdx.x;
    const float* pb = pool + (size_t)b*D128;
    float acc = 0.f;
    for (int i = 0; i < D128; ++i) acc += pb[i]*Wpq[i*D128+j];
    pq[(size_t)b*D128+j] = acc;
}

// KVP[b][n][0:128]=K, [128:256]=V, [256:384]=KP2 ; QA[b][n][0:128]
__global__ __launch_bounds__(512) void prep_kv(const float* __restrict__ enc,
                        const float* __restrict__ attn_k, const float* __restrict__ attn_v,
                        const float* __restrict__ Wkp2, const float* __restrict__ Wqp,
                        const float* __restrict__ pq, int N,
                        float* __restrict__ KVP, float* __restrict__ QA){
    int b = blockIdx.x, t = threadIdx.x;
    int seg = t >> 7, j = t & 127;
    const float* W = (seg==0) ? attn_k : (seg==1) ? attn_v : (seg==2) ? Wkp2 : Wqp;
    float w[128];
    #pragma unroll
    for (int i = 0; i < 128; ++i) w[i] = W[i*D128 + j];
    float pqv = (seg==3) ? pq[(size_t)b*D128 + j] : 0.f;
    const float* eb = enc + (size_t)b*N*D128;
    for (int n = 0; n < N; ++n){
        const float* en = eb + (size_t)n*D128;   // wave-uniform -> scalar loads
        float a0=0.f, a1=0.f, a2=0.f, a3=0.f;
        #pragma unroll
        for (int i = 0; i < 128; i += 4){
            a0 += en[i+0]*w[i+0];
            a1 += en[i+1]*w[i+1];
            a2 += en[i+2]*w[i+2];
            a3 += en[i+3]*w[i+3];
        }
        float acc = (a0+a1)+(a2+a3);
        if (seg < 3) KVP[((size_t)b*N+n)*384 + seg*128 + j] = acc;
        else         QA [((size_t)b*N+n)*D128 + j]          = acc + pqv;
    }
}

// ---------------- sequential decode: one block per batch element ----------------
__global__ __launch_bounds__(TDEC, 1) void decode(
    const float* __restrict__ QA, const float* __restrict__ KVP,
    const float* __restrict__ wlast, const float* __restrict__ demand,
    const float* __restrict__ capv, const void* p_nd, const void* p_temp,
    int n_steps, float* __restrict__ out)
{
    extern __shared__ float sm[];
    int* ibc = (int*)&sm[BC_OFF + 16];
    const int b = blockIdx.x, t = threadIdx.x;
    const int nd = read_scalar_int(p_nd);
    const float temp = read_scalar_float(p_temp);
    const float* dem = demand + (size_t)b*NT;
    const float capb = capv[b];
    const float capfull = capv[0];

    // stage K/V/KP2^T into LDS
    {
        const float* src = KVP + (size_t)b*NT*384;
        for (int i = t; i < NT*384; i += TDEC){
            int n = i / 384, c = i - n*384;
            float vlu = src[i];
            if (c < 128)      sm[KS_OFF  + n*KS_STRIDE + c]            = vlu;
            else if (c < 256) sm[VS_OFF  + n*KS_STRIDE + (c-128)]      = vlu;
            else              sm[KP2_OFF + (c-256)*KP2_STRIDE + n]     = vlu;
        }
    }
    if (t < NT){
        sm[MK1_OFF + t] = 0.0f;
        float mm = (dem[t] > capb) ? 1.0f : 0.0f;   // demand > dyn0
        if (t < nd) mm = 1.0f;                      // go_depot(idx0) && !done
        sm[MK_OFF + t] = mm;
    }
    if (t == 0){ sm[BC_OFF + 0] = capb; ibc[0] = 0; }
    if (t >= 128){
        int d = t - 128;
        sm[QV_OFF + d] = QA[((size_t)b*NT + 0)*D128 + d] + capb*wlast[d];
    }
    int served = 0; float logps = 0.0f;   // live only on thread 0
    __syncthreads();

    for (int s = 0; s < n_steps; ++s){
        // ---- compat = (q . k)/4, masked ----
        {
            int nn = t & 127, hb = t >> 7;
            if (nn < NT){
                #pragma unroll
                for (int it = 0; it < 4; ++it){
                    int h = hb + 2*it;
                    const float* kr = &sm[KS_OFF + nn*KS_STRIDE + h*16];
                    const float* qr = &sm[QV_OFF + h*16];
                    float acc = 0.f;
                    #pragma unroll
                    for (int j = 0; j < 16; ++j) acc += qr[j]*kr[j];
                    acc *= 0.25f;
                    if (sm[MK_OFF + nn] > 0.0f) acc = -1000000000.0f;
                    sm[SC_OFF + h*NT + nn] = acc;
                }
            }
        }
        __syncthreads();
        // ---- per-head softmax (store unnormalized p, sums to bc[8+h]) ----
        {
            int g = t >> 5, s32 = t & 31;
            float m = -3.4e38f;
            #pragma unroll
            for (int k2 = 0; k2 < 4; ++k2){
                int n = s32 + 32*k2;
                if (n < NT) m = fmaxf(m, sm[SC_OFF + g*NT + n]);
            }
            #pragma unroll
            for (int off = 1; off < 32; off <<= 1) m = fmaxf(m, __shfl_xor(m, off, 64));
            float lsum = 0.f;
            #pragma unroll
            for (int k2 = 0; k2 < 4; ++k2){
                int n = s32 + 32*k2;
                if (n < NT){
                    float pv = expf(sm[SC_OFF + g*NT + n] - m);
                    sm[SC_OFF + g*NT + n] = pv;
                    lsum += pv;
                }
            }
            #pragma unroll
            for (int off = 1; off < 32; off <<= 1) lsum += __shfl_xor(lsum, off, 64);
            if (s32 == 0) sm[BC_OFF + 8 + g] = lsum;
        }
        __syncthreads();
        // ---- out0 partials: sum_n p[h][n]*V[n][d] ----
        {
            int d = t & 127, hf = t >> 7, h = d >> 4;
            int n0 = hf ? 51 : 0, n1 = hf ? NT : 51;
            float acc = 0.f;
            for (int n = n0; n < n1; ++n)
                acc += sm[SC_OFF + h*NT + n]*sm[VS_OFF + n*KS_STRIDE + d];
            sm[O0_OFF + hf*128 + d] = acc;
        }
        __syncthreads();
        if (t < 128){
            float o = (sm[O0_OFF + t] + sm[O0_OFF + 128 + t]) / sm[BC_OFF + 8 + (t>>4)];
            sm[O0_OFF + t] = o;
        }
        __syncthreads();
        // ---- logits: tanh(out0 . kp2[n] * inv_d)*10, masked, /temp ----
        float facc = 0.f; int fn = t >> 1, fh = t & 1;
        if (t < 2*NT){
            const float* kp = &sm[KP2_OFF + (fh*64)*KP2_STRIDE + fn];
            const float* oo = &sm[O0_OFF + fh*64];
            #pragma unroll 8
            for (int dd = 0; dd < 64; ++dd) facc += oo[dd]*kp[dd*KP2_STRIDE];
            if (fh) sm[LGP_OFF + fn] = facc;
        }
        __syncthreads();
        if (t < 2*NT && fh == 0){
            float tot = facc + sm[LGP_OFF + fn];
            float l = tanhf(tot*INV_D_CONST)*10.0f;
            if (sm[MK_OFF + fn] > 0.0f) l = -1000000000.0f;
            l = l / temp;
            sm[LG_OFF + fn] = l;
        }
        __syncthreads();
        // ---- argmax (first index wins ties, like jnp.argmax) ----
        if (t < 64){
            float v = (t < NT) ? sm[LG_OFF + t] : -3.4e38f;
            int idx = t;
            if (t + 64 < NT){
                float v2 = sm[LG_OFF + t + 64];
                if (v2 > v){ v = v2; idx = t + 64; }
            }
            #pragma unroll
            for (int off = 1; off < 64; off <<= 1){
                float ov = __shfl_xor(v, off, 64);
                int oi = __shfl_xor(idx, off, 64);
                if (ov > v || (ov == v && oi < idx)){ v = ov; idx = oi; }
            }
            if (t == 0){ sm[BC_OFF + 2] = v; ibc[0] = idx; }
        }
        __syncthreads();
        // ---- exp pass; prefetch next QA row under it ----
        float qreg = 0.f;
        int newIdx = ibc[0];
        if (t < NT) sm[LGP_OFF + t] = expf(sm[LG_OFF + t] - sm[BC_OFF + 2]);
        if (t >= 128) qreg = QA[((size_t)b*NT + newIdx)*D128 + (t - 128)];
        __syncthreads();
        // ---- logsumexp + scalar state update (thread 0) ----
        if (t < 64){
            float ssum = ((t < NT) ? sm[LGP_OFF + t] : 0.f)
                       + ((t + 64 < NT) ? sm[LGP_OFF + t + 64] : 0.f);
            #pragma unroll
            for (int off = 1; off < 64; off <<= 1) ssum += __shfl_xor(ssum, off, 64);
            if (t == 0){
                float logp = -logf(ssum);            // l[idx] == max
                if (served < NT - 1) logps += logp;  // is_done (pre-update mask1)
                int idx = newIdx;
                float sel = dem[idx];
                bool go = (idx < nd);
                float dynN = go ? capfull : (sm[BC_OFF + 0] - sel);
                if (!go && sm[MK1_OFF + idx] == 0.0f){ sm[MK1_OFF + idx] = 1.0f; served++; }
                bool done = (served >= NT - nd);
                sm[BC_OFF + 0] = dynN;
                sm[BC_OFF + 4] = (go && !done) ? 1.0f : 0.0f;
                out[(size_t)b*n_steps + s] = (float)idx;   // actions.T[b][s]
            }
        }
        __syncthreads();
        // ---- mask rebuild + next q ----
        if (t < NT){
            float mm = fmaxf(sm[MK1_OFF + t], (dem[t] > sm[BC_OFF + 0]) ? 1.0f : 0.0f);
            if (t < nd) mm = sm[BC_OFF + 4];
            sm[MK_OFF + t] = mm;
        } else if (t >= 128){
            sm[QV_OFF + (t - 128)] = qreg + sm[BC_OFF + 0]*wlast[t - 128];
        }
        __syncthreads();
    }
    if (t == 0){
        int B = gridDim.x;
        out[(size_t)B*n_steps + b] = logps;
    }
}

extern "C" void kernel_launch(void* const* d_in, const int* in_sizes, int n_in,
                              void* d_out, int out_size, void* d_ws, size_t ws_size,
                              hipStream_t stream) {
    const float* enc     = (const float*)d_in[0];
    const float* pool    = (const float*)d_in[1];
    const float* capv    = (const float*)d_in[2];
    const float* demand  = (const float*)d_in[3];
    const float* fc_w    = (const float*)d_in[4];
    const float* fc1_w   = (const float*)d_in[5];
    const float* attn_w  = (const float*)d_in[6];
    const float* attn_k  = (const float*)d_in[7];
    const float* attn_v  = (const float*)d_in[8];
    const float* attn_fc = (const float*)d_in[9];
    const float* prob_k  = (const float*)d_in[10];
    const void*  p_nd    = d_in[12];
    const void*  p_temp  = d_in[13];

    int B = in_sizes[1] / D128;          // pool is (B, D)
    int N = in_sizes[3] / B;             // demand is (B, N); must equal NT
    int n_steps = out_size / B - 1;      // out = B*n_steps actions + B logps

    float* ws    = (float*)d_ws;
    float* Wkp2  = ws;
    float* Wqp   = Wkp2 + 16384;
    float* Wpq   = Wqp + 16384;
    float* wlast = Wpq + 16384;
    float* pq    = wlast + 128;
    float* KVP   = pq + (size_t)B*D128;
    float* QA    = KVP + (size_t)B*N*384;

    prep_w <<<385, 128, 0, stream>>>(fc_w, fc1_w, attn_w, prob_k, attn_fc, Wkp2, Wqp, Wpq, wlast);
    prep_pq<<<B,   128, 0, stream>>>(pool, Wpq, pq);
    prep_kv<<<B,   512, 0, stream>>>(enc, attn_k, attn_v, Wkp2, Wqp, pq, N, KVP, QA);

    size_t smem = (size_t)LDS_FLOATS * sizeof(float);
    hipFuncSetAttribute((const void*)decode, hipFuncAttributeMaxDynamicSharedMemorySize, (int)smem);
    decode<<<B, TDEC, smem, stream>>>(QA, KVP, wlast, demand, capv, p_nd, p_temp,
                                      n_steps, (float*)d_out);
}

// Round 2
// 1845.788 us; speedup vs baseline: 2.6189x; 2.6189x over previous
//
#include <hip/hip_runtime.h>

#define D128 128
#define NT 101
#define ND_PAD 104
#define TDEC 512

// ---- decode LDS layout (floats) ----
#define KP2T_OFF 0                      // 128 x 101 col-major kp2 (kp2t[d][n])
#define P_OFF    12928                  // 8 x 104 unnormalized scores
#define O_OFF    13760                  // 128
#define QV_OFF   13888                  // 128
#define LGH_OFF  14016                  // 4 x 104 logit partials
#define LG_OFF   14432                  // 104
#define MK_OFF   14536                  // 104
#define MK1_OFF  14640                  // 104
#define DM_OFF   14744                  // 104
#define BC_OFF   14848                  // 32 scalars
#define LDS_FLOATS 14880                // 59520 B -> 2 blocks/CU

#define INV_D_CONST 0.08838834764831845f

__device__ __forceinline__ int read_scalar_int(const void* p){
    unsigned u = *(const unsigned*)p;
    if (u < 1000000u) return (int)u;
    return (int)__uint_as_float(u);
}
__device__ __forceinline__ float read_scalar_float(const void* p){
    unsigned u = *(const unsigned*)p;
    if (u < 1000000u) return (float)(int)u;
    return __uint_as_float(u);
}

// ---------------- weight folding ----------------
// Wcat[128][512]: cols 0-127 attn_k, 128-255 attn_v, 256-383 Wkp2, 384-511 Wqp
// Wkp2[i][j] = sum_e prob_k[i][e]*attn_fc[j][e]
// Wqp [i][j] = sum_e fc_w[i][e]*attn_w[e][j]
// wlast[j]   = sum_e fc_w[128][e]*attn_w[e][j]
__global__ __launch_bounds__(512) void prep_w2(
        const float* __restrict__ fc_w, const float* __restrict__ attn_w,
        const float* __restrict__ prob_k, const float* __restrict__ attn_fc,
        const float* __restrict__ attn_k, const float* __restrict__ attn_v,
        float* __restrict__ Wcat, float* __restrict__ wlast){
    int i = blockIdx.x, t = threadIdx.x;
    if (i < 128){
        if (t < 128){
            Wcat[i*512 + t] = attn_k[i*D128 + t];
        } else if (t < 256){
            int j = t - 128;
            Wcat[i*512 + 128 + j] = attn_v[i*D128 + j];
        } else if (t < 384){
            int j = t - 256; float acc = 0.f;
            for (int e = 0; e < D128; ++e) acc += prob_k[i*D128+e]*attn_fc[j*D128+e];
            Wcat[i*512 + 256 + j] = acc;
        } else {
            int j = t - 384; float acc = 0.f;
            for (int e = 0; e < D128; ++e) acc += fc_w[i*D128+e]*attn_w[e*D128+j];
            Wcat[i*512 + 384 + j] = acc;
        }
    } else if (t < 128){
        float acc = 0.f;
        for (int e = 0; e < D128; ++e) acc += fc_w[128*D128+e]*attn_w[e*D128+t];
        wlast[t] = acc;
    }
}

// pq[b] = (pool[b] @ fc1_w) @ attn_w
__global__ __launch_bounds__(128) void prep_pq(
        const float* __restrict__ pool, const float* __restrict__ fc1_w,
        const float* __restrict__ attn_w, float* __restrict__ pq){
    __shared__ float s1[128], s2[128];
    int b = blockIdx.x, t = threadIdx.x;
    s1[t] = pool[(size_t)b*D128 + t];
    __syncthreads();
    float a = 0.f;
    for (int i = 0; i < D128; ++i) a += s1[i]*fc1_w[i*D128 + t];
    s2[t] = a;
    __syncthreads();
    float a2 = 0.f;
    for (int i = 0; i < D128; ++i) a2 += s2[i]*attn_w[i*D128 + t];
    pq[(size_t)b*D128 + t] = a2;
}

// C[m][c] = enc_flat[m] @ Wcat[:, c] ; c<384 -> KVP, c>=384 -> QA (+pq)
__global__ __launch_bounds__(256) void gemm_prep(
        const float* __restrict__ enc, const float* __restrict__ Wcat,
        const float* __restrict__ pq, int M,
        float* __restrict__ KVP, float* __restrict__ QA){
    __shared__ float As[64*132];
    const int t = threadIdx.x;
    const int m0 = blockIdx.x * 64;
    const int cb0 = blockIdx.y * 64;
    for (int i = t; i < 64*32; i += 256){
        int row = i >> 5, c4 = (i & 31) << 2;
        float4 val = make_float4(0.f,0.f,0.f,0.f);
        if (m0 + row < M) val = *(const float4*)(enc + (size_t)(m0+row)*D128 + c4);
        *(float4*)&As[row*132 + c4] = val;
    }
    __syncthreads();
    const int tx = t & 15, ty = t >> 4;
    float acc[4][4];
    #pragma unroll
    for (int i = 0; i < 4; ++i)
        #pragma unroll
        for (int j = 0; j < 4; ++j) acc[i][j] = 0.f;
    const float* wp = Wcat + cb0 + tx*4;
    #pragma unroll 4
    for (int k = 0; k < 128; ++k){
        float4 bv = *(const float4*)(wp + (size_t)k*512);
        float a0 = As[(ty*4+0)*132 + k];
        float a1 = As[(ty*4+1)*132 + k];
        float a2 = As[(ty*4+2)*132 + k];
        float a3 = As[(ty*4+3)*132 + k];
        acc[0][0] += a0*bv.x; acc[0][1] += a0*bv.y; acc[0][2] += a0*bv.z; acc[0][3] += a0*bv.w;
        acc[1][0] += a1*bv.x; acc[1][1] += a1*bv.y; acc[1][2] += a1*bv.z; acc[1][3] += a1*bv.w;
        acc[2][0] += a2*bv.x; acc[2][1] += a2*bv.y; acc[2][2] += a2*bv.z; acc[2][3] += a2*bv.w;
        acc[3][0] += a3*bv.x; acc[3][1] += a3*bv.y; acc[3][2] += a3*bv.z; acc[3][3] += a3*bv.w;
    }
    #pragma unroll
    for (int rr = 0; rr < 4; ++rr){
        int m = m0 + ty*4 + rr;
        if (m >= M) continue;
        if (cb0 < 384){
            *(float4*)&KVP[(size_t)m*384 + cb0 + tx*4] =
                make_float4(acc[rr][0], acc[rr][1], acc[rr][2], acc[rr][3]);
        } else {
            int bb = m / NT;
            int c = cb0 - 384 + tx*4;
            float4 pv = *(const float4*)(pq + (size_t)bb*D128 + c);
            *(float4*)&QA[(size_t)m*D128 + c] =
                make_float4(acc[rr][0]+pv.x, acc[rr][1]+pv.y, acc[rr][2]+pv.z, acc[rr][3]+pv.w);
        }
    }
}

// ---------------- sequential decode: one block (8 waves = 8 heads) per batch ----------------
__global__ __launch_bounds__(TDEC, 4) void decode(
    const float* __restrict__ QA, const float* __restrict__ KVP,
    const float* __restrict__ wlast, const float* __restrict__ demand,
    const float* __restrict__ capv, const void* p_nd, const void* p_temp,
    int n_steps, float* __restrict__ out)
{
    extern __shared__ float sm[];
    const int b = blockIdx.x, t = threadIdx.x;
    const int l = t & 63, g = t >> 6;          // lane, wave(=head)
    const int nd = read_scalar_int(p_nd);
    const float temp = read_scalar_float(p_temp);
    const float capb = capv[b], capfull = capv[0];
    const long mb = (long)b * NT;

    // ---- K fragment (head g) into registers: rows l and l+64 ----
    float k0[16], k1[16];
    {
        const float* kr = KVP + (mb + l)*384 + g*16;
        float4 a = *(const float4*)(kr+0), bq = *(const float4*)(kr+4);
        float4 c = *(const float4*)(kr+8), d = *(const float4*)(kr+12);
        k0[0]=a.x; k0[1]=a.y; k0[2]=a.z; k0[3]=a.w;
        k0[4]=bq.x; k0[5]=bq.y; k0[6]=bq.z; k0[7]=bq.w;
        k0[8]=c.x; k0[9]=c.y; k0[10]=c.z; k0[11]=c.w;
        k0[12]=d.x; k0[13]=d.y; k0[14]=d.z; k0[15]=d.w;
    }
    if (l < 37){
        const float* kr = KVP + (mb + l + 64)*384 + g*16;
        float4 a = *(const float4*)(kr+0), bq = *(const float4*)(kr+4);
        float4 c = *(const float4*)(kr+8), d = *(const float4*)(kr+12);
        k1[0]=a.x; k1[1]=a.y; k1[2]=a.z; k1[3]=a.w;
        k1[4]=bq.x; k1[5]=bq.y; k1[6]=bq.z; k1[7]=bq.w;
        k1[8]=c.x; k1[9]=c.y; k1[10]=c.z; k1[11]=c.w;
        k1[12]=d.x; k1[13]=d.y; k1[14]=d.z; k1[15]=d.w;
    } else {
        #pragma unroll
        for (int j = 0; j < 16; ++j) k1[j] = 0.f;
    }
    // ---- V column slice (head g, dim d16, n-quarter qq) into registers ----
    const int d16 = l & 15, qq = l >> 4;
    float v[26];
    #pragma unroll
    for (int i = 0; i < 26; ++i){
        int n = qq*26 + i;
        v[i] = (n < NT) ? KVP[(mb + n)*384 + 128 + g*16 + d16] : 0.f;
    }
    // ---- stage kp2^T [d][n] into LDS ----
    for (int i = t; i < NT*128; i += TDEC){
        int n = i >> 7, d = i & 127;
        sm[KP2T_OFF + d*NT + n] = KVP[(mb + n)*384 + 256 + d];
    }
    float wl = 0.f;
    if (t < NT){
        float dv = demand[mb + t];
        sm[DM_OFF + t] = dv;
        sm[MK1_OFF + t] = 0.f;
        float mm = (dv > capb) ? 1.f : 0.f;
        if (t < nd) mm = 1.f;
        sm[MK_OFF + t] = mm;
    }
    if (t >= 384){
        int d = t - 384;
        wl = wlast[d];
        sm[QV_OFF + d] = QA[(mb + 0)*D128 + d] + capb*wl;
    }
    if (t == 0){ sm[BC_OFF + 0] = capb; sm[BC_OFF + 1] = 0.f; }
    int served = 0; float logps = 0.f;      // live on thread 0
    __syncthreads();

    for (int s = 0; s < n_steps; ++s){
        // ---- P1 (per wave g): compat -> softmax -> PV, all wave-internal ----
        float q[16];
        {
            const float4* qp = (const float4*)&sm[QV_OFF + g*16];
            float4 q4 = qp[0]; q[0]=q4.x; q[1]=q4.y; q[2]=q4.z; q[3]=q4.w;
            q4 = qp[1]; q[4]=q4.x; q[5]=q4.y; q[6]=q4.z; q[7]=q4.w;
            q4 = qp[2]; q[8]=q4.x; q[9]=q4.y; q[10]=q4.z; q[11]=q4.w;
            q4 = qp[3]; q[12]=q4.x; q[13]=q4.y; q[14]=q4.z; q[15]=q4.w;
        }
        float c1 = 0.f;
        #pragma unroll
        for (int j = 0; j < 16; ++j) c1 += q[j]*k0[j];
        c1 *= 0.25f;
        if (sm[MK_OFF + l] > 0.f) c1 = -1000000000.0f;
        float c2 = -1000000000.0f;
        if (l < 37){
            float a = 0.f;
            #pragma unroll
            for (int j = 0; j < 16; ++j) a += q[j]*k1[j];
            a *= 0.25f;
            if (sm[MK_OFF + l + 64] > 0.f) a = -1000000000.0f;
            c2 = a;
        }
        float m = fmaxf(c1, c2);
        #pragma unroll
        for (int off = 1; off < 64; off <<= 1) m = fmaxf(m, __shfl_xor(m, off, 64));
        float p1 = expf(c1 - m);
        float p2 = expf(c2 - m);                 // 0 for lanes >= 37
        float ls = p1 + p2;
        #pragma unroll
        for (int off = 1; off < 64; off <<= 1) ls += __shfl_xor(ls, off, 64);
        sm[P_OFF + g*ND_PAD + l] = p1;
        if (l < 40) sm[P_OFF + g*ND_PAD + l + 64] = p2;   // covers pads 101..103 with 0
        float acc = 0.f;
        #pragma unroll
        for (int i = 0; i < 26; ++i) acc += sm[P_OFF + g*ND_PAD + qq*26 + i] * v[i];
        acc += __shfl_xor(acc, 16, 64);
        acc += __shfl_xor(acc, 32, 64);
        if (l < 16) sm[O_OFF + g*16 + l] = acc / ls;
        __syncthreads();                                   // A

        // ---- P2: logits partials (404 threads, rotated quarters, 2-way banks) ----
        if (t < 404){
            int fn = t >> 2, fq = t & 3;
            int base = fq << 5, rot = fq << 3;
            float a = 0.f;
            #pragma unroll
            for (int j = 0; j < 32; ++j){
                int dd = base + ((j + rot) & 31);
                a += sm[O_OFF + dd] * sm[KP2T_OFF + dd*NT + fn];
            }
            sm[LGH_OFF + fq*ND_PAD + fn] = a;
        }
        __syncthreads();                                   // B

        // ---- P3: finalize logits ----
        if (t < NT){
            float s0 = sm[LGH_OFF + 0*ND_PAD + t], s1 = sm[LGH_OFF + 1*ND_PAD + t];
            float s2 = sm[LGH_OFF + 2*ND_PAD + t], s3 = sm[LGH_OFF + 3*ND_PAD + t];
            float tot = (s0 + s1) + (s2 + s3);
            float lg = tanhf(tot * INV_D_CONST) * 10.0f;
            if (sm[MK_OFF + t] > 0.f) lg = -1000000000.0f;
            sm[LG_OFF + t] = lg / temp;
        }
        __syncthreads();                                   // C

        // ---- P4: argmax (redundant in waves 0,6,7) + lse + bookkeeping + QA prefetch ----
        float qreg = 0.f;
        if (t < 64 || t >= 384){
            float v1 = sm[LG_OFF + l];
            float v2 = (l < 37) ? sm[LG_OFF + l + 64] : -3.4e38f;
            float bv = v1; int bi = l;
            if (v2 > bv){ bv = v2; bi = l + 64; }
            #pragma unroll
            for (int off = 1; off < 64; off <<= 1){
                float ov = __shfl_xor(bv, off, 64);
                int oi = __shfl_xor(bi, off, 64);
                if (ov > bv || (ov == bv && oi < bi)){ bv = ov; bi = oi; }
            }
            if (t >= 384) qreg = QA[(mb + bi)*D128 + (t - 384)];
            if (t < 64){
                float e1 = expf(v1 - bv);
                float e2 = (l < 37) ? expf(v2 - bv) : 0.f;
                float ss = e1 + e2;
                #pragma unroll
                for (int off = 1; off < 64; off <<= 1) ss += __shfl_xor(ss, off, 64);
                if (t == 0){
                    if (served < NT - 1) logps += -logf(ss);   // l[idx]==max
                    int idx = bi;
                    float sel = sm[DM_OFF + idx];
                    bool go = idx < nd;
                    float dynO = sm[BC_OFF + 0];
                    float dynN = go ? capfull : (dynO - sel);
                    if (!go && sm[MK1_OFF + idx] == 0.f){ sm[MK1_OFF + idx] = 1.f; served++; }
                    bool done = served >= NT - nd;
                    sm[BC_OFF + 0] = dynN;
                    sm[BC_OFF + 1] = (go && !done) ? 1.f : 0.f;
                    out[(size_t)b*n_steps + s] = (float)idx;
                }
            }
        }
        __syncthreads();                                   // D

        // ---- P5: mask rebuild || q update ----
        if (t < NT){
            float mm = fmaxf(sm[MK1_OFF + t], (sm[DM_OFF + t] > sm[BC_OFF + 0]) ? 1.f : 0.f);
            if (t < nd) mm = sm[BC_OFF + 1];
            sm[MK_OFF + t] = mm;
        } else if (t >= 384){
            sm[QV_OFF + (t - 384)] = qreg + sm[BC_OFF + 0]*wl;
        }
        __syncthreads();                                   // E
    }
    if (t == 0) out[(size_t)gridDim.x*n_steps + b] = logps;
}

extern "C" void kernel_launch(void* const* d_in, const int* in_sizes, int n_in,
                              void* d_out, int out_size, void* d_ws, size_t ws_size,
                              hipStream_t stream) {
    const float* enc     = (const float*)d_in[0];
    const float* pool    = (const float*)d_in[1];
    const float* capv    = (const float*)d_in[2];
    const float* demand  = (const float*)d_in[3];
    const float* fc_w    = (const float*)d_in[4];
    const float* fc1_w   = (const float*)d_in[5];
    const float* attn_w  = (const float*)d_in[6];
    const float* attn_k  = (const float*)d_in[7];
    const float* attn_v  = (const float*)d_in[8];
    const float* attn_fc = (const float*)d_in[9];
    const float* prob_k  = (const float*)d_in[10];
    const void*  p_nd    = d_in[12];
    const void*  p_temp  = d_in[13];

    int B = in_sizes[1] / D128;          // pool is (B, D)
    int N = in_sizes[3] / B;             // demand is (B, N) == NT
    (void)N;
    int n_steps = out_size / B - 1;      // out = B*n_steps actions + B logps
    int M = B * NT;

    float* ws    = (float*)d_ws;
    float* Wcat  = ws;                               // 128*512
    float* wlast = Wcat + 128*512;                   // 128
    float* pq    = wlast + 128;                      // B*128
    float* KVP   = pq + (size_t)B*D128;              // M*384
    float* QA    = KVP + (size_t)M*384;              // M*128

    prep_w2<<<129, 512, 0, stream>>>(fc_w, attn_w, prob_k, attn_fc, attn_k, attn_v, Wcat, wlast);
    prep_pq<<<B, 128, 0, stream>>>(pool, fc1_w, attn_w, pq);
    dim3 ggrid((M + 63)/64, 8);
    gemm_prep<<<ggrid, 256, 0, stream>>>(enc, Wcat, pq, M, KVP, QA);

    size_t smem = (size_t)LDS_FLOATS * sizeof(float);
    decode<<<B, TDEC, smem, stream>>>(QA, KVP, wlast, demand, capv, p_nd, p_temp,
                                      n_steps, (float*)d_out);
}

// Round 3
// 1284.578 us; speedup vs baseline: 3.7630x; 1.4369x over previous
//
#include <hip/hip_runtime.h>

#define D128 128
#define NT 101
#define TDEC 512
#define PSTR 112            // padded p row: 4 quarters of 28 floats (16B aligned)

// ---- decode LDS layout (floats) ----
#define P_OFF    0                    // 8 x PSTR   (zero-padded tails)
#define O_OFFS   (P_OFF + 8*PSTR)     // 128
#define QRAW_OFF (O_OFFS + 128)       // 128  raw QA row of current idx
#define LGH_OFF  (QRAW_OFF + 128)     // 8 x 104 logit partials per dim-block
#define BC_OFF   (LGH_OFF + 8*104)    // 16 broadcast scalars
#define LDS_FLOATS (BC_OFF + 16)      // ~2000 floats = 8 KB

#define INV_D_CONST 0.08838834764831845f

__device__ __forceinline__ int read_scalar_int(const void* p){
    unsigned u = *(const unsigned*)p;
    if (u < 1000000u) return (int)u;
    return (int)__uint_as_float(u);
}
__device__ __forceinline__ float read_scalar_float(const void* p){
    unsigned u = *(const unsigned*)p;
    if (u < 1000000u) return (float)(int)u;
    return __uint_as_float(u);
}

// ---- DPP cross-lane helpers (VALU pipe, no DS) ----
template<int C> __device__ __forceinline__ float dppf(float x){
    return __int_as_float(__builtin_amdgcn_update_dpp(
        __float_as_int(x), __float_as_int(x), C, 0xF, 0xF, false));
}
template<int C> __device__ __forceinline__ int dppi(int x){
    return __builtin_amdgcn_update_dpp(x, x, C, 0xF, 0xF, false);
}
// 0xB1 quad_perm(1,0,3,2)=xor1 ; 0x4E quad_perm(2,3,0,1)=xor2 ;
// 0x141 row_half_mirror (xor7 after quad stages) ; 0x140 row_mirror (xor15)
__device__ __forceinline__ float wave_sum64(float v){
    v += dppf<0xB1>(v); v += dppf<0x4E>(v); v += dppf<0x141>(v); v += dppf<0x140>(v);
    v += __shfl_xor(v, 16, 64); v += __shfl_xor(v, 32, 64); return v;
}
__device__ __forceinline__ float wave_max64(float v){
    v = fmaxf(v, dppf<0xB1>(v)); v = fmaxf(v, dppf<0x4E>(v));
    v = fmaxf(v, dppf<0x141>(v)); v = fmaxf(v, dppf<0x140>(v));
    v = fmaxf(v, __shfl_xor(v, 16, 64)); v = fmaxf(v, __shfl_xor(v, 32, 64)); return v;
}
__device__ __forceinline__ void wave_argmax64(float& v, int& i){
    { float ov = dppf<0xB1>(v);        int oi = dppi<0xB1>(i);        if (ov>v || (ov==v && oi<i)){v=ov;i=oi;} }
    { float ov = dppf<0x4E>(v);        int oi = dppi<0x4E>(i);        if (ov>v || (ov==v && oi<i)){v=ov;i=oi;} }
    { float ov = dppf<0x141>(v);       int oi = dppi<0x141>(i);       if (ov>v || (ov==v && oi<i)){v=ov;i=oi;} }
    { float ov = dppf<0x140>(v);       int oi = dppi<0x140>(i);       if (ov>v || (ov==v && oi<i)){v=ov;i=oi;} }
    { float ov = __shfl_xor(v,16,64);  int oi = __shfl_xor(i,16,64);  if (ov>v || (ov==v && oi<i)){v=ov;i=oi;} }
    { float ov = __shfl_xor(v,32,64);  int oi = __shfl_xor(i,32,64);  if (ov>v || (ov==v && oi<i)){v=ov;i=oi;} }
}

// ---------------- weight folding (unchanged from R2) ----------------
__global__ __launch_bounds__(512) void prep_w2(
        const float* __restrict__ fc_w, const float* __restrict__ attn_w,
        const float* __restrict__ prob_k, const float* __restrict__ attn_fc,
        const float* __restrict__ attn_k, const float* __restrict__ attn_v,
        float* __restrict__ Wcat, float* __restrict__ wlast){
    int i = blockIdx.x, t = threadIdx.x;
    if (i < 128){
        if (t < 128){
            Wcat[i*512 + t] = attn_k[i*D128 + t];
        } else if (t < 256){
            int j = t - 128;
            Wcat[i*512 + 128 + j] = attn_v[i*D128 + j];
        } else if (t < 384){
            int j = t - 256; float acc = 0.f;
            for (int e = 0; e < D128; ++e) acc += prob_k[i*D128+e]*attn_fc[j*D128+e];
            Wcat[i*512 + 256 + j] = acc;
        } else {
            int j = t - 384; float acc = 0.f;
            for (int e = 0; e < D128; ++e) acc += fc_w[i*D128+e]*attn_w[e*D128+j];
            Wcat[i*512 + 384 + j] = acc;
        }
    } else if (t < 128){
        float acc = 0.f;
        for (int e = 0; e < D128; ++e) acc += fc_w[128*D128+e]*attn_w[e*D128+t];
        wlast[t] = acc;
    }
}

__global__ __launch_bounds__(128) void prep_pq(
        const float* __restrict__ pool, const float* __restrict__ fc1_w,
        const float* __restrict__ attn_w, float* __restrict__ pq){
    __shared__ float s1[128], s2[128];
    int b = blockIdx.x, t = threadIdx.x;
    s1[t] = pool[(size_t)b*D128 + t];
    __syncthreads();
    float a = 0.f;
    for (int i = 0; i < D128; ++i) a += s1[i]*fc1_w[i*D128 + t];
    s2[t] = a;
    __syncthreads();
    float a2 = 0.f;
    for (int i = 0; i < D128; ++i) a2 += s2[i]*attn_w[i*D128 + t];
    pq[(size_t)b*D128 + t] = a2;
}

__global__ __launch_bounds__(256) void gemm_prep(
        const float* __restrict__ enc, const float* __restrict__ Wcat,
        const float* __restrict__ pq, int M,
        float* __restrict__ KVP, float* __restrict__ QA){
    __shared__ float As[64*132];
    const int t = threadIdx.x;
    const int m0 = blockIdx.x * 64;
    const int cb0 = blockIdx.y * 64;
    for (int i = t; i < 64*32; i += 256){
        int row = i >> 5, c4 = (i & 31) << 2;
        float4 val = make_float4(0.f,0.f,0.f,0.f);
        if (m0 + row < M) val = *(const float4*)(enc + (size_t)(m0+row)*D128 + c4);
        *(float4*)&As[row*132 + c4] = val;
    }
    __syncthreads();
    const int tx = t & 15, ty = t >> 4;
    float acc[4][4];
    #pragma unroll
    for (int i = 0; i < 4; ++i)
        #pragma unroll
        for (int j = 0; j < 4; ++j) acc[i][j] = 0.f;
    const float* wp = Wcat + cb0 + tx*4;
    #pragma unroll 4
    for (int k = 0; k < 128; ++k){
        float4 bv = *(const float4*)(wp + (size_t)k*512);
        float a0 = As[(ty*4+0)*132 + k];
        float a1 = As[(ty*4+1)*132 + k];
        float a2 = As[(ty*4+2)*132 + k];
        float a3 = As[(ty*4+3)*132 + k];
        acc[0][0] += a0*bv.x; acc[0][1] += a0*bv.y; acc[0][2] += a0*bv.z; acc[0][3] += a0*bv.w;
        acc[1][0] += a1*bv.x; acc[1][1] += a1*bv.y; acc[1][2] += a1*bv.z; acc[1][3] += a1*bv.w;
        acc[2][0] += a2*bv.x; acc[2][1] += a2*bv.y; acc[2][2] += a2*bv.z; acc[2][3] += a2*bv.w;
        acc[3][0] += a3*bv.x; acc[3][1] += a3*bv.y; acc[3][2] += a3*bv.z; acc[3][3] += a3*bv.w;
    }
    #pragma unroll
    for (int rr = 0; rr < 4; ++rr){
        int m = m0 + ty*4 + rr;
        if (m >= M) continue;
        if (cb0 < 384){
            *(float4*)&KVP[(size_t)m*384 + cb0 + tx*4] =
                make_float4(acc[rr][0], acc[rr][1], acc[rr][2], acc[rr][3]);
        } else {
            int bb = m / NT;
            int c = cb0 - 384 + tx*4;
            float4 pv = *(const float4*)(pq + (size_t)bb*D128 + c);
            *(float4*)&QA[(size_t)m*D128 + c] =
                make_float4(acc[rr][0]+pv.x, acc[rr][1]+pv.y, acc[rr][2]+pv.z, acc[rr][3]+pv.w);
        }
    }
}

// ---------------- sequential decode: 8 waves (= 8 heads / dim-blocks) per batch elem ----------------
__global__ __launch_bounds__(TDEC, 4) void decode(
    const float* __restrict__ QA, const float* __restrict__ KVP,
    const float* __restrict__ wlast, const float* __restrict__ demand,
    const float* __restrict__ capv, const void* p_nd, const void* p_temp,
    int n_steps, float* __restrict__ out)
{
    __shared__ float sm[LDS_FLOATS];
    const int b = blockIdx.x, t = threadIdx.x;
    const int l = t & 63, g = t >> 6;          // lane, wave (= head = dim-block)
    const int d16 = l & 15, qq = l >> 4;       // PV mapping
    const int nd = read_scalar_int(p_nd);
    const float temp = read_scalar_float(p_temp);
    const float capfull = capv[0];
    float dyn = capv[b];
    const long mb = (long)b * NT;
    const bool hasB = (l < NT - 64);           // second-row validity (l < 37)

    // ---- K rows (head g) ----
    float k0[16], k1[16];
    {
        const float* kr = KVP + (mb + l)*384 + g*16;
        #pragma unroll
        for (int j4 = 0; j4 < 4; ++j4){
            float4 a = *(const float4*)(kr + j4*4);
            k0[j4*4+0]=a.x; k0[j4*4+1]=a.y; k0[j4*4+2]=a.z; k0[j4*4+3]=a.w;
        }
    }
    if (hasB){
        const float* kr = KVP + (mb + l + 64)*384 + g*16;
        #pragma unroll
        for (int j4 = 0; j4 < 4; ++j4){
            float4 a = *(const float4*)(kr + j4*4);
            k1[j4*4+0]=a.x; k1[j4*4+1]=a.y; k1[j4*4+2]=a.z; k1[j4*4+3]=a.w;
        }
    } else {
        #pragma unroll
        for (int j = 0; j < 16; ++j) k1[j] = 0.f;
    }
    // kwl = wlast_g . k_row
    float kwl1 = 0.f, kwl2 = 0.f;
    {
        #pragma unroll
        for (int j = 0; j < 16; ++j){
            float w = wlast[g*16 + j];
            kwl1 += w*k0[j]; kwl2 += w*k1[j];
        }
    }
    // ---- V column slice: dim d16 of head g, n = qq*28 + i ----
    float vv[28];
    #pragma unroll
    for (int i = 0; i < 28; ++i){
        int n = qq*28 + i;
        vv[i] = (n < NT) ? KVP[(mb + n)*384 + 128 + g*16 + d16] : 0.f;
    }
    // ---- kp2 rows (dims 16g..16g+16) for n = l, l+64 ----
    float p2a[16], p2b[16];
    {
        const float* kr = KVP + (mb + l)*384 + 256 + g*16;
        #pragma unroll
        for (int j4 = 0; j4 < 4; ++j4){
            float4 a = *(const float4*)(kr + j4*4);
            p2a[j4*4+0]=a.x; p2a[j4*4+1]=a.y; p2a[j4*4+2]=a.z; p2a[j4*4+3]=a.w;
        }
    }
    if (hasB){
        const float* kr = KVP + (mb + l + 64)*384 + 256 + g*16;
        #pragma unroll
        for (int j4 = 0; j4 < 4; ++j4){
            float4 a = *(const float4*)(kr + j4*4);
            p2b[j4*4+0]=a.x; p2b[j4*4+1]=a.y; p2b[j4*4+2]=a.z; p2b[j4*4+3]=a.w;
        }
    } else {
        #pragma unroll
        for (int j = 0; j < 16; ++j) p2b[j] = 0.f;
    }
    // ---- demand + mask registers ----
    float dem1 = demand[mb + l];
    float dem2 = hasB ? demand[mb + l + 64] : 0.f;
    float mk1a = 0.f, mk1b = 0.f;
    float m1 = (l < nd) ? 1.f : ((dem1 > dyn) ? 1.f : 0.f);
    float m2 = ((l + 64) < nd) ? 1.f : ((dem2 > dyn) ? 1.f : 0.f);
    int served = 0; float logps = 0.f;         // tracked uniformly in wave 0

    // zero P (incl. pads), stage initial QA row 0
    for (int i = t; i < 8*PSTR; i += TDEC) sm[P_OFF + i] = 0.f;
    if (g >= 6){
        int d = (g - 6)*64 + l;
        sm[QRAW_OFF + d] = QA[(mb + 0)*D128 + d];
    }
    __syncthreads();

    for (int s = 0; s < n_steps; ++s){
        // ==== P1: compat -> softmax -> PV (wave-internal) ====
        float qv[16];
        {
            const float4* qp = (const float4*)&sm[QRAW_OFF + g*16];
            #pragma unroll
            for (int j4 = 0; j4 < 4; ++j4){
                float4 q4 = qp[j4];
                qv[j4*4+0]=q4.x; qv[j4*4+1]=q4.y; qv[j4*4+2]=q4.z; qv[j4*4+3]=q4.w;
            }
        }
        float qk1 = 0.f, qk2 = 0.f;
        #pragma unroll
        for (int j = 0; j < 16; ++j){ qk1 += qv[j]*k0[j]; qk2 += qv[j]*k1[j]; }
        float c1 = 0.25f*(qk1 + dyn*kwl1);
        if (m1 > 0.f) c1 = -1000000000.0f;
        float c2 = -1000000000.0f;
        if (hasB){
            float a = 0.25f*(qk2 + dyn*kwl2);
            c2 = (m2 > 0.f) ? -1000000000.0f : a;
        }
        float mx = wave_max64(fmaxf(c1, c2));
        float p1 = expf(c1 - mx);
        float p2v = hasB ? expf(c2 - mx) : 0.f;
        float ls = wave_sum64(p1 + p2v);
        sm[P_OFF + g*PSTR + l] = p1;
        if (hasB) sm[P_OFF + g*PSTR + 64 + l] = p2v;
        __syncthreads();   // ensure own-wave p visible (and O/LGH WAR from prev step)
        // PV: out[d16] partial over this lane's 28 n's
        float acc = 0.f;
        {
            const float4* pp = (const float4*)&sm[P_OFF + g*PSTR + qq*28];
            #pragma unroll
            for (int i4 = 0; i4 < 7; ++i4){
                float4 pv = pp[i4];
                acc += pv.x*vv[i4*4+0] + pv.y*vv[i4*4+1] + pv.z*vv[i4*4+2] + pv.w*vv[i4*4+3];
            }
        }
        acc += __shfl_xor(acc, 16, 64);
        acc += __shfl_xor(acc, 32, 64);
        if (l < 16) sm[O_OFFS + g*16 + l] = acc / ls;
        __syncthreads();                                   // A

        // ==== P2: logit partials for dim-block g (kp2 in regs) ====
        float ov[16];
        {
            const float4* op = (const float4*)&sm[O_OFFS + g*16];
            #pragma unroll
            for (int j4 = 0; j4 < 4; ++j4){
                float4 o4 = op[j4];
                ov[j4*4+0]=o4.x; ov[j4*4+1]=o4.y; ov[j4*4+2]=o4.z; ov[j4*4+3]=o4.w;
            }
        }
        float lg1 = 0.f, lg2 = 0.f;
        #pragma unroll
        for (int j = 0; j < 16; ++j){ lg1 += ov[j]*p2a[j]; lg2 += ov[j]*p2b[j]; }
        sm[LGH_OFF + g*104 + l] = lg1;
        if (hasB) sm[LGH_OFF + g*104 + 64 + l] = lg2;
        __syncthreads();                                   // B

        // ==== finalize: waves 0,6,7 (argmax redundant; wave0 lse+bookkeeping; 6,7 QA prefetch) ====
        float qreg = 0.f;
        if (g == 0 || g >= 6){
            float s1 = 0.f;
            #pragma unroll
            for (int w = 0; w < 8; ++w) s1 += sm[LGH_OFF + w*104 + l];
            float L1 = tanhf(s1 * INV_D_CONST) * 10.0f;
            if (m1 > 0.f) L1 = -1000000000.0f;
            L1 /= temp;
            float L2 = -3.4e38f;
            if (hasB){
                float s2 = 0.f;
                #pragma unroll
                for (int w = 0; w < 8; ++w) s2 += sm[LGH_OFF + w*104 + 64 + l];
                float z = tanhf(s2 * INV_D_CONST) * 10.0f;
                if (m2 > 0.f) z = -1000000000.0f;
                L2 = z / temp;
            }
            float bv = L1; int bi = l;
            if (L2 > bv){ bv = L2; bi = l + 64; }
            wave_argmax64(bv, bi);
            if (g >= 6){
                int d = (g - 6)*64 + l;
                qreg = QA[(mb + bi)*D128 + d];
            } else {
                float e1 = expf(L1 - bv);
                float e2 = hasB ? expf(L2 - bv) : 0.f;
                float ss = wave_sum64(e1 + e2);
                // uniform bookkeeping across wave 0
                float selv = (bi < 64) ? __shfl(dem1, bi, 64) : __shfl(dem2, bi - 64, 64);
                float vis  = (bi < 64) ? __shfl(mk1a, bi, 64) : __shfl(mk1b, bi - 64, 64);
                bool go = bi < nd;
                if (served < NT - 1) logps += -logf(ss);     // pre-update is_done
                float dynN = go ? capfull : (dyn - selv);
                if (!go && vis == 0.f) served++;
                bool done = served >= NT - nd;
                float depotf = (go && !done) ? 1.f : 0.f;
                if (l == 0){
                    *(float4*)&sm[BC_OFF] = make_float4(dynN, depotf, (float)bi, 0.f);
                    out[(size_t)b*n_steps + s] = (float)bi;
                }
            }
        }
        if (g >= 6) sm[QRAW_OFF + (g - 6)*64 + l] = qreg;
        __syncthreads();                                   // D

        // ==== all waves: consume broadcast, update register state (VALU only) ====
        float4 bc = *(const float4*)&sm[BC_OFF];
        dyn = bc.x;
        float depotf = bc.y;
        int idxu = (int)bc.z;
        if (idxu == l && l >= nd) mk1a = 1.f;
        if (hasB && idxu == (l + 64) && (l + 64) >= nd) mk1b = 1.f;
        m1 = fmaxf(mk1a, (dem1 > dyn) ? 1.f : 0.f);
        if (l < nd) m1 = depotf;
        m2 = fmaxf(mk1b, (dem2 > dyn) ? 1.f : 0.f);
        if ((l + 64) < nd) m2 = depotf;
    }
    if (t == 0) out[(size_t)gridDim.x*n_steps + b] = logps;
}

extern "C" void kernel_launch(void* const* d_in, const int* in_sizes, int n_in,
                              void* d_out, int out_size, void* d_ws, size_t ws_size,
                              hipStream_t stream) {
    const float* enc     = (const float*)d_in[0];
    const float* pool    = (const float*)d_in[1];
    const float* capv    = (const float*)d_in[2];
    const float* demand  = (const float*)d_in[3];
    const float* fc_w    = (const float*)d_in[4];
    const float* fc1_w   = (const float*)d_in[5];
    const float* attn_w  = (const float*)d_in[6];
    const float* attn_k  = (const float*)d_in[7];
    const float* attn_v  = (const float*)d_in[8];
    const float* attn_fc = (const float*)d_in[9];
    const float* prob_k  = (const float*)d_in[10];
    const void*  p_nd    = d_in[12];
    const void*  p_temp  = d_in[13];

    int B = in_sizes[1] / D128;          // pool is (B, D)
    int n_steps = out_size / B - 1;      // out = B*n_steps actions + B logps
    int M = B * NT;

    float* ws    = (float*)d_ws;
    float* Wcat  = ws;                               // 128*512
    float* wlast = Wcat + 128*512;                   // 128
    float* pq    = wlast + 128;                      // B*128
    float* KVP   = pq + (size_t)B*D128;              // M*384
    float* QA    = KVP + (size_t)M*384;              // M*128

    prep_w2<<<129, 512, 0, stream>>>(fc_w, attn_w, prob_k, attn_fc, attn_k, attn_v, Wcat, wlast);
    prep_pq<<<B, 128, 0, stream>>>(pool, fc1_w, attn_w, pq);
    dim3 ggrid((M + 63)/64, 8);
    gemm_prep<<<ggrid, 256, 0, stream>>>(enc, Wcat, pq, M, KVP, QA);

    decode<<<B, TDEC, 0, stream>>>(QA, KVP, wlast, demand, capv, p_nd, p_temp,
                                   n_steps, (float*)d_out);
}